// Round 16
// baseline (207.427 us; speedup 1.0000x reference)
//
#include <hip/hip_runtime.h>
#include <cstdint>

// Problem constants (fixed by the reference: B=64, C*H*W = 524288, f32 in/out)
#define BROWS 64
#define NCOL  524288
#define CHUNKS 32
#define CHUNK  (NCOL / CHUNKS)   // 16384 elements per block
#define NV4    (CHUNK / 4)       // 4096 float4 per block
#define LCAP   1536              // per-block candidate staging (expect ~530, +6sig ~670)
#define ECAP   512               // boundary-tie list (expect < 64)
#define MAXCAP 24576             // per-row candidate cap (expect ~17k at 14-bit)
#define M_SAMP 32768             // samples per row (n/M = 16)
#define SEGS   128               // contiguous 256-elem sample segments
#define SBLK   16                // sampling blocks per row
#define SLACK  5200              // ~6 sigma rank slack for the bracket
#define HB2    16384             // 14-bit sample histogram bins per row

// Workspace layout (bytes). hist and cand OVERLAP intentionally: hist is dead
// after k_pick, before k_main writes cand (stream-ordered).
#define ABV_OFF   0u
#define CCNT_OFF  256u
#define RINFO_OFF 512u
#define HIST_OFF  4096u
#define CAND_OFF  4096u
#define ZWORDS    (1024 + BROWS * HB2)   // counters + hist, in u32 words (4.2MB)

// Monotonic map: s1 > s2  <=>  fkey(s1) > fkey(s2)  (as uint32)
__device__ __forceinline__ uint32_t fkey(float s) {
  uint32_t b = __float_as_uint(s);
  return (b & 0x80000000u) ? ~b : (b | 0x80000000u);
}

__global__ __launch_bounds__(256) void k_zero(uint32_t* __restrict__ p, int n) {
  int i = blockIdx.x * 256 + threadIdx.x;
  if (i < n) p[i] = 0;
}

// P0a: distributed sampling. Per-BLOCK 14-bit LDS histogram (64KB, 2 blocks/CU),
// flushed once as sparse global atomics (R12's proven aux fix).
__global__ __launch_bounds__(256) void k_sampleA(const float* __restrict__ x,
                                                 const float* __restrict__ g,
                                                 uint32_t* __restrict__ hist) {
  __shared__ uint32_t h[HB2];  // 64 KB = per-WG LDS limit
  for (int i = threadIdx.x; i < HB2; i += 256) h[i] = 0;
  __syncthreads();
  int row = blockIdx.y;
  size_t rb = (size_t)row * NCOL;
  int i0 = blockIdx.x * (M_SAMP / SBLK);
  for (int it = 0; it < (M_SAMP / SBLK) / 256; ++it) {
    int i = i0 + it * 256 + threadIdx.x;
    size_t off = rb + (size_t)(i >> 8) * (NCOL / SEGS) + (i & 255);
    uint32_t key = fkey(x[off] / 10.0f + g[off]);
    atomicAdd(&h[key >> 18], 1u);
  }
  __syncthreads();
  uint32_t* gh = hist + (size_t)row * HB2;
  for (int i = threadIdx.x; i < HB2; i += 256) {
    uint32_t v = h[i];
    if (v) atomicAdd(&gh[i], v);
  }
}

// P0b: per-row bracket [keyLo, keyHi] from the 14-bit histogram; zero counters.
__global__ __launch_bounds__(1024) void k_pick(const uint32_t* __restrict__ hist,
                                               const int* __restrict__ kptr,
                                               uint32_t* __restrict__ rinfo,
                                               uint32_t* __restrict__ abv,
                                               uint32_t* __restrict__ ccnt) {
  __shared__ uint32_t part[1024];
  __shared__ uint32_t segbuf[16];
  __shared__ uint32_t sel[4];
  int row = blockIdx.x;
  if (threadIdx.x == 0) { abv[row] = 0; ccnt[row] = 0; }
  const uint32_t* gh = hist + (size_t)row * HB2;
  const uint4* gh4 = (const uint4*)gh;
  uint32_t s = 0;
  #pragma unroll
  for (int j = 0; j < 4; ++j) {  // 16 bins per thread
    uint4 v = gh4[threadIdx.x * 4 + j];
    s += v.x + v.y + v.z + v.w;
  }
  part[threadIdx.x] = s;
  __syncthreads();
  if (threadIdx.x == 0) {
    uint32_t kk = (uint32_t)(*kptr);
    uint32_t rHi = ((kk > SLACK ? kk - SLACK : 0u) / 16u) + 1u;  // sample rank from top
    uint32_t rLo = ((kk + SLACK) / 16u) + 1u;
    if (rLo > M_SAMP) rLo = M_SAMP;
    uint32_t cum = 0, cumHi = 0, cumLo = 0;
    int segHi = -1, segLo = -1;
    for (int t = 1023; t >= 0; --t) {
      uint32_t c = part[t];
      if (segHi < 0 && cum + c >= rHi) { segHi = t; cumHi = cum; }
      if (segLo < 0 && cum + c >= rLo) { segLo = t; cumLo = cum; break; }
      cum += c;
    }
    if (segHi < 0) segHi = 0;
    if (segLo < 0) segLo = 0;
    sel[0] = (uint32_t)segHi; sel[1] = rHi - cumHi;
    sel[2] = (uint32_t)segLo; sel[3] = rLo - cumLo;
  }
  __syncthreads();
  int segHi = (int)sel[0], segLo = (int)sel[2];
  if (threadIdx.x < 16) segbuf[threadIdx.x] = gh[segHi * 16 + threadIdx.x];
  __syncthreads();
  if (threadIdx.x == 0) {
    uint32_t rem = sel[1], cum = 0;
    int bin = 0;
    for (int b = 15; b >= 0; --b) {
      uint32_t c = segbuf[b];
      if (cum + c >= rem) { bin = b; break; }
      cum += c;
    }
    uint32_t binHi = (uint32_t)(segHi * 16 + bin);
    rinfo[row * 4 + 0] = (binHi << 18) | 0x3FFFFu;  // top of bin
  }
  __syncthreads();
  if (threadIdx.x < 16) segbuf[threadIdx.x] = gh[segLo * 16 + threadIdx.x];
  __syncthreads();
  if (threadIdx.x == 0) {
    uint32_t rem = sel[3], cum = 0;
    int bin = 0;
    for (int b = 15; b >= 0; --b) {
      uint32_t c = segbuf[b];
      if (cum + c >= rem) { bin = b; break; }
      cum += c;
    }
    uint32_t binLo = (uint32_t)(segLo * 16 + bin);
    rinfo[row * 4 + 1] = binLo << 18;               // bottom of bin
  }
}

// P1: single full pass, PLAIN float4 stores (R8's fastest k_main: plain stores
// complete into L2 in ~100cy and never occupy the vmcnt oldest-op slot; NT
// stores drain at HBM latency and serialize every load-wait). cval carried so
// finalize never re-reads x. LDS 18.7KB -> 8 blocks/CU.
__global__ __launch_bounds__(256) void k_main(const float* __restrict__ x,
                                              const float* __restrict__ g,
                                              const uint32_t* __restrict__ rinfo,
                                              uint64_t* __restrict__ cand,
                                              float* __restrict__ cval,
                                              uint32_t* __restrict__ ccnt,
                                              uint32_t* __restrict__ abv,
                                              float* __restrict__ out, int cap) {
  __shared__ uint64_t lbuf[LCAP];
  __shared__ float lval[LCAP];
  __shared__ uint32_t lcnt, lbase;
  __shared__ uint32_t wsum[4];
  int row = blockIdx.y, chunk = blockIdx.x;
  uint32_t keyHi = rinfo[row * 4 + 0];
  uint32_t keyLo = rinfo[row * 4 + 1];
  if (threadIdx.x == 0) lcnt = 0;
  __syncthreads();
  size_t base = (size_t)row * NCOL + (size_t)chunk * CHUNK;
  const float4* x4 = (const float4*)(x + base);
  const float4* g4 = (const float4*)(g + base);
  float4* o4 = (float4*)(out + base);
  uint32_t mycnt = 0;
  for (int i = threadIdx.x; i < NV4; i += 256) {
    float4 a = x4[i];
    float4 b = g4[i];
    uint32_t f0 = fkey(a.x / 10.0f + b.x);
    uint32_t f1 = fkey(a.y / 10.0f + b.y);
    uint32_t f2 = fkey(a.z / 10.0f + b.z);
    uint32_t f3 = fkey(a.w / 10.0f + b.w);
    float4 o;
    o.x = (f0 > keyHi) ? fmaxf(a.x, 0.0f) : 0.0f;
    o.y = (f1 > keyHi) ? fmaxf(a.y, 0.0f) : 0.0f;
    o.z = (f2 > keyHi) ? fmaxf(a.z, 0.0f) : 0.0f;
    o.w = (f3 > keyHi) ? fmaxf(a.w, 0.0f) : 0.0f;
    o4[i] = o;
    mycnt += (f0 > keyHi) + (f1 > keyHi) + (f2 > keyHi) + (f3 > keyHi);
    uint32_t li = (uint32_t)(chunk * CHUNK + i * 4);
    if (f0 >= keyLo && f0 <= keyHi) { uint32_t p = atomicAdd(&lcnt, 1u); if (p < LCAP) { lbuf[p] = ((uint64_t)f0 << 32) | li;        lval[p] = fmaxf(a.x, 0.0f); } }
    if (f1 >= keyLo && f1 <= keyHi) { uint32_t p = atomicAdd(&lcnt, 1u); if (p < LCAP) { lbuf[p] = ((uint64_t)f1 << 32) | (li + 1u); lval[p] = fmaxf(a.y, 0.0f); } }
    if (f2 >= keyLo && f2 <= keyHi) { uint32_t p = atomicAdd(&lcnt, 1u); if (p < LCAP) { lbuf[p] = ((uint64_t)f2 << 32) | (li + 2u); lval[p] = fmaxf(a.z, 0.0f); } }
    if (f3 >= keyLo && f3 <= keyHi) { uint32_t p = atomicAdd(&lcnt, 1u); if (p < LCAP) { lbuf[p] = ((uint64_t)f3 << 32) | (li + 3u); lval[p] = fmaxf(a.w, 0.0f); } }
  }
  for (int off = 32; off > 0; off >>= 1) mycnt += __shfl_down(mycnt, off);
  int lane = threadIdx.x & 63, wid = threadIdx.x >> 6;
  if (lane == 0) wsum[wid] = mycnt;
  __syncthreads();
  if (threadIdx.x == 0) {
    atomicAdd(&abv[row], wsum[0] + wsum[1] + wsum[2] + wsum[3]);
    lbase = atomicAdd(&ccnt[row], lcnt < LCAP ? lcnt : (uint32_t)LCAP);
  }
  __syncthreads();
  uint32_t cnt = lcnt < LCAP ? lcnt : (uint32_t)LCAP;
  uint64_t* dst = cand + (size_t)row * (size_t)cap;
  float* dv = cval + (size_t)row * (size_t)cap;
  for (uint32_t i = threadIdx.x; i < cnt; i += 256) {
    uint32_t p = lbase + i;
    if (p < (uint32_t)cap) { dst[p] = lbuf[i]; dv[p] = lval[i]; }
  }
}

// P2: exact top-(k - above) among candidates: dynamic-shift 4096-bin radix,
// then sort boundary sub-bin by (key desc, idx asc) -- jax tie semantics.
// Reads cval (L2-resident), NOT x (except <=64 boundary ties).
__global__ __launch_bounds__(256) void k_finalize(const float* __restrict__ x,
                                                  const uint64_t* __restrict__ cand,
                                                  const float* __restrict__ cval,
                                                  const uint32_t* __restrict__ ccnt,
                                                  const uint32_t* __restrict__ abv,
                                                  const uint32_t* __restrict__ rinfo,
                                                  const int* __restrict__ kptr,
                                                  float* __restrict__ out, int cap) {
  __shared__ uint32_t h[4096];
  __shared__ uint32_t part[256];
  __shared__ uint64_t elist[ECAP];
  __shared__ uint32_t ecnt;
  __shared__ int s_cut, s_need2;
  int row = blockIdx.x;
  uint32_t m = ccnt[row];
  if (m > (uint32_t)cap) m = (uint32_t)cap;
  int need = (int)((uint32_t)(*kptr)) - (int)abv[row];
  if (need <= 0) return;
  size_t rb = (size_t)row * NCOL;
  const uint64_t* c = cand + (size_t)row * (size_t)cap;
  const float* cv = cval + (size_t)row * (size_t)cap;
  if ((uint32_t)need >= m) {  // all candidates win
    for (uint32_t i = threadIdx.x; i < m; i += 256) {
      uint32_t idx = (uint32_t)c[i];
      out[rb + idx] = cv[i];
    }
    return;
  }
  uint32_t keyLo = rinfo[row * 4 + 1];
  uint32_t range = rinfo[row * 4 + 0] - keyLo;
  int bits = 32 - __clz((int)(range | 1u));
  int shift = bits > 12 ? bits - 12 : 0;
  for (int i = threadIdx.x; i < 4096; i += 256) h[i] = 0;
  if (threadIdx.x == 0) ecnt = 0;
  __syncthreads();
  for (uint32_t i = threadIdx.x; i < m; i += 256) {
    uint32_t key = (uint32_t)(c[i] >> 32);
    atomicAdd(&h[(key - keyLo) >> shift], 1u);
  }
  __syncthreads();
  uint32_t s = 0;
  for (int j = 0; j < 16; ++j) s += h[threadIdx.x * 16 + j];
  part[threadIdx.x] = s;
  __syncthreads();
  if (threadIdx.x == 0) {
    uint32_t cum = 0;
    int seg = 255;
    for (; seg > 0; --seg) {
      if (cum + part[seg] >= (uint32_t)need) break;
      cum += part[seg];
    }
    int bin = seg * 16 + 15;
    for (; bin > seg * 16; --bin) {
      if (cum + h[bin] >= (uint32_t)need) break;
      cum += h[bin];
    }
    s_cut = bin;
    s_need2 = need - (int)cum;
  }
  __syncthreads();
  int cut = s_cut, need2 = s_need2;
  for (uint32_t i = threadIdx.x; i < m; i += 256) {
    uint64_t e = c[i];
    int bin = (int)(((uint32_t)(e >> 32) - keyLo) >> shift);
    if (bin > cut) {
      out[rb + (uint32_t)e] = cv[i];
    } else if (bin == cut) {
      uint32_t p = atomicAdd(&ecnt, 1u);
      if (p < ECAP) elist[p] = e ^ 0xFFFFFFFFull;  // key desc, idx asc under u64 desc
    }
  }
  __syncthreads();
  int mm = (int)(ecnt < (uint32_t)ECAP ? ecnt : (uint32_t)ECAP);
  for (int pass = 0; pass < mm; ++pass) {
    for (int i = threadIdx.x; 2 * i + (pass & 1) + 1 < mm; i += 256) {
      int a2 = 2 * i + (pass & 1);
      uint64_t va = elist[a2], vb = elist[a2 + 1];
      if (vb > va) { elist[a2] = vb; elist[a2 + 1] = va; }
    }
    __syncthreads();
  }
  int w = need2 < mm ? need2 : mm;
  for (int i = threadIdx.x; i < w; i += 256) {
    uint32_t idx = ~(uint32_t)elist[i];
    out[rb + idx] = fmaxf(x[rb + idx], 0.0f);
  }
}

extern "C" void kernel_launch(void* const* d_in, const int* in_sizes, int n_in,
                              void* d_out, int out_size, void* d_ws, size_t ws_size,
                              hipStream_t stream) {
  const float* x = (const float*)d_in[0];
  const float* g = (const float*)d_in[1];
  const int* kptr = (const int*)d_in[2];
  float* out = (float*)d_out;
  char* ws = (char*)d_ws;

  uint32_t* abv = (uint32_t*)(ws + ABV_OFF);
  uint32_t* ccnt = (uint32_t*)(ws + CCNT_OFF);
  uint32_t* rinfo = (uint32_t*)(ws + RINFO_OFF);
  uint32_t* hist = (uint32_t*)(ws + HIST_OFF);
  uint64_t* cand = (uint64_t*)(ws + CAND_OFF);  // overlaps hist (hist dead by then)

  // cand: 8B/entry, cval: 4B/entry -> 12B per candidate slot
  long cap_avail = ((long)ws_size - (long)CAND_OFF) / (12 * BROWS);
  int cap = cap_avail < MAXCAP ? (int)cap_avail : MAXCAP;
  if (cap < 1) cap = 1;
  float* cval = (float*)(ws + CAND_OFF + (size_t)BROWS * (size_t)cap * 8u);

  k_zero<<<(ZWORDS + 255) / 256, 256, 0, stream>>>((uint32_t*)ws, ZWORDS);
  dim3 sgrid(SBLK, BROWS);
  k_sampleA<<<sgrid, 256, 0, stream>>>(x, g, hist);
  k_pick<<<BROWS, 1024, 0, stream>>>(hist, kptr, rinfo, abv, ccnt);
  dim3 grid(CHUNKS, BROWS);
  k_main<<<grid, 256, 0, stream>>>(x, g, rinfo, cand, cval, ccnt, abv, out, cap);
  k_finalize<<<BROWS, 256, 0, stream>>>(x, cand, cval, ccnt, abv, rinfo, kptr, out, cap);
}

// Round 17
// 185.616 us; speedup vs baseline: 1.1175x; 1.1175x over previous
//
#include <hip/hip_runtime.h>
#include <cstdint>

// Problem constants (fixed by the reference: B=64, C*H*W = 524288, f32 in/out)
#define BROWS 64
#define NCOL  524288
#define CHUNKS 32
#define CHUNK  (NCOL / CHUNKS)   // 16384 elements per block
#define NV4    (CHUNK / 4)       // 4096 float4 per block
#define LCAP   1536              // per-block candidate staging (expect ~530, +6sig ~670)
#define ECAP   512               // boundary-tie list (expect < 64)
#define MAXCAP 24576             // per-row candidate cap (expect ~17k at 14-bit)
#define M_SAMP 32768             // samples per row (n/M = 16)
#define SEGS   128               // contiguous 256-elem sample segments
#define SBLK   16                // sampling blocks per row
#define SLACK  5200              // ~6 sigma rank slack for the bracket
#define HB2    16384             // 14-bit sample histogram bins per row

typedef float nf4 __attribute__((ext_vector_type(4)));  // native vec for nontemporal store

// Workspace layout (bytes). hist and cand OVERLAP intentionally: hist is dead
// after k_pick, before k_main writes cand (stream-ordered).
#define ABV_OFF   0u
#define CCNT_OFF  256u
#define RINFO_OFF 512u
#define HIST_OFF  4096u
#define CAND_OFF  4096u
#define ZWORDS    (1024 + BROWS * HB2)   // counters + hist, in u32 words (4.2MB)

// Monotonic map: s1 > s2  <=>  fkey(s1) > fkey(s2)  (as uint32)
__device__ __forceinline__ uint32_t fkey(float s) {
  uint32_t b = __float_as_uint(s);
  return (b & 0x80000000u) ? ~b : (b | 0x80000000u);
}

// P0a: distributed sampling. Per-BLOCK 14-bit LDS histogram (64KB, 2 blocks/CU),
// flushed once as sparse global atomics (R12's proven aux fix).
__global__ __launch_bounds__(256) void k_sampleA(const float* __restrict__ x,
                                                 const float* __restrict__ g,
                                                 uint32_t* __restrict__ hist) {
  __shared__ uint32_t h[HB2];  // 64 KB = per-WG LDS limit
  for (int i = threadIdx.x; i < HB2; i += 256) h[i] = 0;
  __syncthreads();
  int row = blockIdx.y;
  size_t rb = (size_t)row * NCOL;
  int i0 = blockIdx.x * (M_SAMP / SBLK);
  for (int it = 0; it < (M_SAMP / SBLK) / 256; ++it) {
    int i = i0 + it * 256 + threadIdx.x;
    size_t off = rb + (size_t)(i >> 8) * (NCOL / SEGS) + (i & 255);
    uint32_t key = fkey(x[off] / 10.0f + g[off]);
    atomicAdd(&h[key >> 18], 1u);
  }
  __syncthreads();
  uint32_t* gh = hist + (size_t)row * HB2;
  for (int i = threadIdx.x; i < HB2; i += 256) {
    uint32_t v = h[i];
    if (v) atomicAdd(&gh[i], v);
  }
}

// P0b: per-row bracket [keyLo, keyHi] from the 14-bit histogram; zero counters.
__global__ __launch_bounds__(1024) void k_pick(const uint32_t* __restrict__ hist,
                                               const int* __restrict__ kptr,
                                               uint32_t* __restrict__ rinfo,
                                               uint32_t* __restrict__ abv,
                                               uint32_t* __restrict__ ccnt) {
  __shared__ uint32_t part[1024];
  __shared__ uint32_t segbuf[16];
  __shared__ uint32_t sel[4];
  int row = blockIdx.x;
  if (threadIdx.x == 0) { abv[row] = 0; ccnt[row] = 0; }
  const uint32_t* gh = hist + (size_t)row * HB2;
  const uint4* gh4 = (const uint4*)gh;
  uint32_t s = 0;
  #pragma unroll
  for (int j = 0; j < 4; ++j) {  // 16 bins per thread
    uint4 v = gh4[threadIdx.x * 4 + j];
    s += v.x + v.y + v.z + v.w;
  }
  part[threadIdx.x] = s;
  __syncthreads();
  if (threadIdx.x == 0) {
    uint32_t kk = (uint32_t)(*kptr);
    uint32_t rHi = ((kk > SLACK ? kk - SLACK : 0u) / 16u) + 1u;  // sample rank from top
    uint32_t rLo = ((kk + SLACK) / 16u) + 1u;
    if (rLo > M_SAMP) rLo = M_SAMP;
    uint32_t cum = 0, cumHi = 0, cumLo = 0;
    int segHi = -1, segLo = -1;
    for (int t = 1023; t >= 0; --t) {
      uint32_t c = part[t];
      if (segHi < 0 && cum + c >= rHi) { segHi = t; cumHi = cum; }
      if (segLo < 0 && cum + c >= rLo) { segLo = t; cumLo = cum; break; }
      cum += c;
    }
    if (segHi < 0) segHi = 0;
    if (segLo < 0) segLo = 0;
    sel[0] = (uint32_t)segHi; sel[1] = rHi - cumHi;
    sel[2] = (uint32_t)segLo; sel[3] = rLo - cumLo;
  }
  __syncthreads();
  int segHi = (int)sel[0], segLo = (int)sel[2];
  if (threadIdx.x < 16) segbuf[threadIdx.x] = gh[segHi * 16 + threadIdx.x];
  __syncthreads();
  if (threadIdx.x == 0) {
    uint32_t rem = sel[1], cum = 0;
    int bin = 0;
    for (int b = 15; b >= 0; --b) {
      uint32_t c = segbuf[b];
      if (cum + c >= rem) { bin = b; break; }
      cum += c;
    }
    uint32_t binHi = (uint32_t)(segHi * 16 + bin);
    rinfo[row * 4 + 0] = (binHi << 18) | 0x3FFFFu;  // top of bin
  }
  __syncthreads();
  if (threadIdx.x < 16) segbuf[threadIdx.x] = gh[segLo * 16 + threadIdx.x];
  __syncthreads();
  if (threadIdx.x == 0) {
    uint32_t rem = sel[3], cum = 0;
    int bin = 0;
    for (int b = 15; b >= 0; --b) {
      uint32_t c = segbuf[b];
      if (cum + c >= rem) { bin = b; break; }
      cum += c;
    }
    uint32_t binLo = (uint32_t)(segLo * 16 + bin);
    rinfo[row * 4 + 1] = binLo << 18;               // bottom of bin
  }
}

// P1: single full pass (R12's proven k_main: NT out-store pays the write drain
// inline, which the R8/R16 A/B showed is cheaper than polluting L2/L3 for aux).
// cval carried at LCAP=1536 (18.9KB LDS, 8 blocks/CU -- R16-proven footprint).
__global__ __launch_bounds__(256) void k_main(const float* __restrict__ x,
                                              const float* __restrict__ g,
                                              const uint32_t* __restrict__ rinfo,
                                              uint64_t* __restrict__ cand,
                                              float* __restrict__ cval,
                                              uint32_t* __restrict__ ccnt,
                                              uint32_t* __restrict__ abv,
                                              float* __restrict__ out, int cap) {
  __shared__ uint64_t lbuf[LCAP];
  __shared__ float lval[LCAP];
  __shared__ uint32_t lcnt, lbase;
  __shared__ uint32_t wsum[4];
  int row = blockIdx.y, chunk = blockIdx.x;
  uint32_t keyHi = rinfo[row * 4 + 0];
  uint32_t keyLo = rinfo[row * 4 + 1];
  if (threadIdx.x == 0) lcnt = 0;
  __syncthreads();
  size_t base = (size_t)row * NCOL + (size_t)chunk * CHUNK;
  const float4* x4 = (const float4*)(x + base);
  const float4* g4 = (const float4*)(g + base);
  nf4* o4 = (nf4*)(out + base);
  uint32_t mycnt = 0;
  for (int i = threadIdx.x; i < NV4; i += 256) {
    float4 a = x4[i];
    float4 b = g4[i];
    uint32_t f0 = fkey(a.x / 10.0f + b.x);
    uint32_t f1 = fkey(a.y / 10.0f + b.y);
    uint32_t f2 = fkey(a.z / 10.0f + b.z);
    uint32_t f3 = fkey(a.w / 10.0f + b.w);
    nf4 o;
    o.x = (f0 > keyHi) ? fmaxf(a.x, 0.0f) : 0.0f;
    o.y = (f1 > keyHi) ? fmaxf(a.y, 0.0f) : 0.0f;
    o.z = (f2 > keyHi) ? fmaxf(a.z, 0.0f) : 0.0f;
    o.w = (f3 > keyHi) ? fmaxf(a.w, 0.0f) : 0.0f;
    __builtin_nontemporal_store(o, &o4[i]);
    mycnt += (f0 > keyHi) + (f1 > keyHi) + (f2 > keyHi) + (f3 > keyHi);
    uint32_t li = (uint32_t)(chunk * CHUNK + i * 4);
    if (f0 >= keyLo && f0 <= keyHi) { uint32_t p = atomicAdd(&lcnt, 1u); if (p < LCAP) { lbuf[p] = ((uint64_t)f0 << 32) | li;        lval[p] = fmaxf(a.x, 0.0f); } }
    if (f1 >= keyLo && f1 <= keyHi) { uint32_t p = atomicAdd(&lcnt, 1u); if (p < LCAP) { lbuf[p] = ((uint64_t)f1 << 32) | (li + 1u); lval[p] = fmaxf(a.y, 0.0f); } }
    if (f2 >= keyLo && f2 <= keyHi) { uint32_t p = atomicAdd(&lcnt, 1u); if (p < LCAP) { lbuf[p] = ((uint64_t)f2 << 32) | (li + 2u); lval[p] = fmaxf(a.z, 0.0f); } }
    if (f3 >= keyLo && f3 <= keyHi) { uint32_t p = atomicAdd(&lcnt, 1u); if (p < LCAP) { lbuf[p] = ((uint64_t)f3 << 32) | (li + 3u); lval[p] = fmaxf(a.w, 0.0f); } }
  }
  for (int off = 32; off > 0; off >>= 1) mycnt += __shfl_down(mycnt, off);
  int lane = threadIdx.x & 63, wid = threadIdx.x >> 6;
  if (lane == 0) wsum[wid] = mycnt;
  __syncthreads();
  if (threadIdx.x == 0) {
    atomicAdd(&abv[row], wsum[0] + wsum[1] + wsum[2] + wsum[3]);
    lbase = atomicAdd(&ccnt[row], lcnt < LCAP ? lcnt : (uint32_t)LCAP);
  }
  __syncthreads();
  uint32_t cnt = lcnt < LCAP ? lcnt : (uint32_t)LCAP;
  uint64_t* dst = cand + (size_t)row * (size_t)cap;
  float* dv = cval + (size_t)row * (size_t)cap;
  for (uint32_t i = threadIdx.x; i < cnt; i += 256) {
    uint32_t p = lbase + i;
    if (p < (uint32_t)cap) { dst[p] = lbuf[i]; dv[p] = lval[i]; }
  }
}

// P2: exact top-(k - above) among candidates: dynamic-shift 4096-bin radix,
// then sort boundary sub-bin by (key desc, idx asc) -- jax tie semantics.
// Reads cval (L2-resident), NOT x (except <=64 boundary ties).
__global__ __launch_bounds__(256) void k_finalize(const float* __restrict__ x,
                                                  const uint64_t* __restrict__ cand,
                                                  const float* __restrict__ cval,
                                                  const uint32_t* __restrict__ ccnt,
                                                  const uint32_t* __restrict__ abv,
                                                  const uint32_t* __restrict__ rinfo,
                                                  const int* __restrict__ kptr,
                                                  float* __restrict__ out, int cap) {
  __shared__ uint32_t h[4096];
  __shared__ uint32_t part[256];
  __shared__ uint64_t elist[ECAP];
  __shared__ uint32_t ecnt;
  __shared__ int s_cut, s_need2;
  int row = blockIdx.x;
  uint32_t m = ccnt[row];
  if (m > (uint32_t)cap) m = (uint32_t)cap;
  int need = (int)((uint32_t)(*kptr)) - (int)abv[row];
  if (need <= 0) return;
  size_t rb = (size_t)row * NCOL;
  const uint64_t* c = cand + (size_t)row * (size_t)cap;
  const float* cv = cval + (size_t)row * (size_t)cap;
  if ((uint32_t)need >= m) {  // all candidates win
    for (uint32_t i = threadIdx.x; i < m; i += 256) {
      uint32_t idx = (uint32_t)c[i];
      out[rb + idx] = cv[i];
    }
    return;
  }
  uint32_t keyLo = rinfo[row * 4 + 1];
  uint32_t range = rinfo[row * 4 + 0] - keyLo;
  int bits = 32 - __clz((int)(range | 1u));
  int shift = bits > 12 ? bits - 12 : 0;
  for (int i = threadIdx.x; i < 4096; i += 256) h[i] = 0;
  if (threadIdx.x == 0) ecnt = 0;
  __syncthreads();
  for (uint32_t i = threadIdx.x; i < m; i += 256) {
    uint32_t key = (uint32_t)(c[i] >> 32);
    atomicAdd(&h[(key - keyLo) >> shift], 1u);
  }
  __syncthreads();
  uint32_t s = 0;
  for (int j = 0; j < 16; ++j) s += h[threadIdx.x * 16 + j];
  part[threadIdx.x] = s;
  __syncthreads();
  if (threadIdx.x == 0) {
    uint32_t cum = 0;
    int seg = 255;
    for (; seg > 0; --seg) {
      if (cum + part[seg] >= (uint32_t)need) break;
      cum += part[seg];
    }
    int bin = seg * 16 + 15;
    for (; bin > seg * 16; --bin) {
      if (cum + h[bin] >= (uint32_t)need) break;
      cum += h[bin];
    }
    s_cut = bin;
    s_need2 = need - (int)cum;
  }
  __syncthreads();
  int cut = s_cut, need2 = s_need2;
  for (uint32_t i = threadIdx.x; i < m; i += 256) {
    uint64_t e = c[i];
    int bin = (int)(((uint32_t)(e >> 32) - keyLo) >> shift);
    if (bin > cut) {
      out[rb + (uint32_t)e] = cv[i];
    } else if (bin == cut) {
      uint32_t p = atomicAdd(&ecnt, 1u);
      if (p < ECAP) elist[p] = e ^ 0xFFFFFFFFull;  // key desc, idx asc under u64 desc
    }
  }
  __syncthreads();
  int mm = (int)(ecnt < (uint32_t)ECAP ? ecnt : (uint32_t)ECAP);
  for (int pass = 0; pass < mm; ++pass) {
    for (int i = threadIdx.x; 2 * i + (pass & 1) + 1 < mm; i += 256) {
      int a2 = 2 * i + (pass & 1);
      uint64_t va = elist[a2], vb = elist[a2 + 1];
      if (vb > va) { elist[a2] = vb; elist[a2 + 1] = va; }
    }
    __syncthreads();
  }
  int w = need2 < mm ? need2 : mm;
  for (int i = threadIdx.x; i < w; i += 256) {
    uint32_t idx = ~(uint32_t)elist[i];
    out[rb + idx] = fmaxf(x[rb + idx], 0.0f);
  }
}

extern "C" void kernel_launch(void* const* d_in, const int* in_sizes, int n_in,
                              void* d_out, int out_size, void* d_ws, size_t ws_size,
                              hipStream_t stream) {
  const float* x = (const float*)d_in[0];
  const float* g = (const float*)d_in[1];
  const int* kptr = (const int*)d_in[2];
  float* out = (float*)d_out;
  char* ws = (char*)d_ws;

  uint32_t* abv = (uint32_t*)(ws + ABV_OFF);
  uint32_t* ccnt = (uint32_t*)(ws + CCNT_OFF);
  uint32_t* rinfo = (uint32_t*)(ws + RINFO_OFF);
  uint32_t* hist = (uint32_t*)(ws + HIST_OFF);
  uint64_t* cand = (uint64_t*)(ws + CAND_OFF);  // overlaps hist (hist dead by then)

  // cand: 8B/entry, cval: 4B/entry -> 12B per candidate slot
  long cap_avail = ((long)ws_size - (long)CAND_OFF) / (12 * BROWS);
  int cap = cap_avail < MAXCAP ? (int)cap_avail : MAXCAP;
  if (cap < 1) cap = 1;
  float* cval = (float*)(ws + CAND_OFF + (size_t)BROWS * (size_t)cap * 8u);

  // async memset node replaces the k_zero launch (graph-capturable)
  hipMemsetAsync(ws, 0, (size_t)ZWORDS * 4u, stream);
  dim3 sgrid(SBLK, BROWS);
  k_sampleA<<<sgrid, 256, 0, stream>>>(x, g, hist);
  k_pick<<<BROWS, 1024, 0, stream>>>(hist, kptr, rinfo, abv, ccnt);
  dim3 grid(CHUNKS, BROWS);
  k_main<<<grid, 256, 0, stream>>>(x, g, rinfo, cand, cval, ccnt, abv, out, cap);
  k_finalize<<<BROWS, 256, 0, stream>>>(x, cand, cval, ccnt, abv, rinfo, kptr, out, cap);
}

// Round 18
// 182.189 us; speedup vs baseline: 1.1385x; 1.0188x over previous
//
#include <hip/hip_runtime.h>
#include <cstdint>

// Problem constants (fixed by the reference: B=64, C*H*W = 524288, f32 in/out)
#define BROWS 64
#define NCOL  524288
#define CHUNKS 32
#define CHUNK  (NCOL / CHUNKS)   // 16384 elements per block
#define NV4    (CHUNK / 4)       // 4096 float4 per block
#define NITER  (NV4 / 256)       // 16 iterations
#define LCAP   1536              // per-block candidate staging (expect ~530, +6sig ~670)
#define ECAP   512               // boundary-tie list (expect < 64)
#define MAXCAP 24576             // per-row candidate cap (expect ~17k at 14-bit)
#define M_SAMP 32768             // samples per row (n/M = 16)
#define SEGS   128               // contiguous 256-elem sample segments
#define SBLK   16                // sampling blocks per row
#define SLACK  5200              // ~6 sigma rank slack for the bracket
#define HB2    16384             // 14-bit sample histogram bins per row

typedef float nf4 __attribute__((ext_vector_type(4)));  // native vec for nontemporal store

// Workspace layout (bytes). hist and cand OVERLAP intentionally: hist is dead
// after k_pick, before k_main writes cand (stream-ordered).
#define ABV_OFF   0u
#define CCNT_OFF  256u
#define RINFO_OFF 512u
#define HIST_OFF  4096u
#define CAND_OFF  4096u
#define ZWORDS    (1024 + BROWS * HB2)   // counters + hist, in u32 words (4.2MB)

// Monotonic map: s1 > s2  <=>  fkey(s1) > fkey(s2)  (as uint32)
__device__ __forceinline__ uint32_t fkey(float s) {
  uint32_t b = __float_as_uint(s);
  return (b & 0x80000000u) ? ~b : (b | 0x80000000u);
}

// P0a: distributed sampling. Per-BLOCK 14-bit LDS histogram (64KB, 2 blocks/CU),
// flushed once as sparse global atomics (R12's proven aux fix).
__global__ __launch_bounds__(256) void k_sampleA(const float* __restrict__ x,
                                                 const float* __restrict__ g,
                                                 uint32_t* __restrict__ hist) {
  __shared__ uint32_t h[HB2];  // 64 KB = per-WG LDS limit
  for (int i = threadIdx.x; i < HB2; i += 256) h[i] = 0;
  __syncthreads();
  int row = blockIdx.y;
  size_t rb = (size_t)row * NCOL;
  int i0 = blockIdx.x * (M_SAMP / SBLK);
  for (int it = 0; it < (M_SAMP / SBLK) / 256; ++it) {
    int i = i0 + it * 256 + threadIdx.x;
    size_t off = rb + (size_t)(i >> 8) * (NCOL / SEGS) + (i & 255);
    uint32_t key = fkey(x[off] / 10.0f + g[off]);
    atomicAdd(&h[key >> 18], 1u);
  }
  __syncthreads();
  uint32_t* gh = hist + (size_t)row * HB2;
  for (int i = threadIdx.x; i < HB2; i += 256) {
    uint32_t v = h[i];
    if (v) atomicAdd(&gh[i], v);
  }
}

// P0b: per-row bracket [keyLo, keyHi] from the 14-bit histogram; zero counters.
__global__ __launch_bounds__(1024) void k_pick(const uint32_t* __restrict__ hist,
                                               const int* __restrict__ kptr,
                                               uint32_t* __restrict__ rinfo,
                                               uint32_t* __restrict__ abv,
                                               uint32_t* __restrict__ ccnt) {
  __shared__ uint32_t part[1024];
  __shared__ uint32_t segbuf[16];
  __shared__ uint32_t sel[4];
  int row = blockIdx.x;
  if (threadIdx.x == 0) { abv[row] = 0; ccnt[row] = 0; }
  const uint32_t* gh = hist + (size_t)row * HB2;
  const uint4* gh4 = (const uint4*)gh;
  uint32_t s = 0;
  #pragma unroll
  for (int j = 0; j < 4; ++j) {  // 16 bins per thread
    uint4 v = gh4[threadIdx.x * 4 + j];
    s += v.x + v.y + v.z + v.w;
  }
  part[threadIdx.x] = s;
  __syncthreads();
  if (threadIdx.x == 0) {
    uint32_t kk = (uint32_t)(*kptr);
    uint32_t rHi = ((kk > SLACK ? kk - SLACK : 0u) / 16u) + 1u;  // sample rank from top
    uint32_t rLo = ((kk + SLACK) / 16u) + 1u;
    if (rLo > M_SAMP) rLo = M_SAMP;
    uint32_t cum = 0, cumHi = 0, cumLo = 0;
    int segHi = -1, segLo = -1;
    for (int t = 1023; t >= 0; --t) {
      uint32_t c = part[t];
      if (segHi < 0 && cum + c >= rHi) { segHi = t; cumHi = cum; }
      if (segLo < 0 && cum + c >= rLo) { segLo = t; cumLo = cum; break; }
      cum += c;
    }
    if (segHi < 0) segHi = 0;
    if (segLo < 0) segLo = 0;
    sel[0] = (uint32_t)segHi; sel[1] = rHi - cumHi;
    sel[2] = (uint32_t)segLo; sel[3] = rLo - cumLo;
  }
  __syncthreads();
  int segHi = (int)sel[0], segLo = (int)sel[2];
  if (threadIdx.x < 16) segbuf[threadIdx.x] = gh[segHi * 16 + threadIdx.x];
  __syncthreads();
  if (threadIdx.x == 0) {
    uint32_t rem = sel[1], cum = 0;
    int bin = 0;
    for (int b = 15; b >= 0; --b) {
      uint32_t c = segbuf[b];
      if (cum + c >= rem) { bin = b; break; }
      cum += c;
    }
    uint32_t binHi = (uint32_t)(segHi * 16 + bin);
    rinfo[row * 4 + 0] = (binHi << 18) | 0x3FFFFu;  // top of bin
  }
  __syncthreads();
  if (threadIdx.x < 16) segbuf[threadIdx.x] = gh[segLo * 16 + threadIdx.x];
  __syncthreads();
  if (threadIdx.x == 0) {
    uint32_t rem = sel[3], cum = 0;
    int bin = 0;
    for (int b = 15; b >= 0; --b) {
      uint32_t c = segbuf[b];
      if (cum + c >= rem) { bin = b; break; }
      cum += c;
    }
    uint32_t binLo = (uint32_t)(segLo * 16 + bin);
    rinfo[row * 4 + 1] = binLo << 18;               // bottom of bin
  }
}

// P1: single full pass, software-pipelined so the NEXT iteration's loads are
// issued BEFORE the NT store. vmcnt retires in order, so with queue order
// [load,load,store] the compiler can wait vmcnt(1) for the loads WITHOUT
// draining the HBM-latency NT store (the R12-NT vs R8-plain 15us gap). NT
// keeps x/g L3-resident for aux (R8/R16 showed plain store costs ~35us there).
__global__ __launch_bounds__(256) void k_main(const float* __restrict__ x,
                                              const float* __restrict__ g,
                                              const uint32_t* __restrict__ rinfo,
                                              uint64_t* __restrict__ cand,
                                              float* __restrict__ cval,
                                              uint32_t* __restrict__ ccnt,
                                              uint32_t* __restrict__ abv,
                                              float* __restrict__ out, int cap) {
  __shared__ uint64_t lbuf[LCAP];
  __shared__ float lval[LCAP];
  __shared__ uint32_t lcnt, lbase;
  __shared__ uint32_t wsum[4];
  int row = blockIdx.y, chunk = blockIdx.x;
  uint32_t keyHi = rinfo[row * 4 + 0];
  uint32_t keyLo = rinfo[row * 4 + 1];
  if (threadIdx.x == 0) lcnt = 0;
  __syncthreads();
  size_t base = (size_t)row * NCOL + (size_t)chunk * CHUNK;
  const float4* x4 = (const float4*)(x + base);
  const float4* g4 = (const float4*)(g + base);
  nf4* o4 = (nf4*)(out + base);
  uint32_t mycnt = 0;

  float4 a = x4[threadIdx.x];
  float4 b = g4[threadIdx.x];
  for (int it = 0; it < NITER; ++it) {
    int i = it * 256 + threadIdx.x;
    uint32_t f0 = fkey(a.x / 10.0f + b.x);
    uint32_t f1 = fkey(a.y / 10.0f + b.y);
    uint32_t f2 = fkey(a.z / 10.0f + b.z);
    uint32_t f3 = fkey(a.w / 10.0f + b.w);
    nf4 o;
    o.x = (f0 > keyHi) ? fmaxf(a.x, 0.0f) : 0.0f;
    o.y = (f1 > keyHi) ? fmaxf(a.y, 0.0f) : 0.0f;
    o.z = (f2 > keyHi) ? fmaxf(a.z, 0.0f) : 0.0f;
    o.w = (f3 > keyHi) ? fmaxf(a.w, 0.0f) : 0.0f;
    // prefetch next iteration BEFORE the NT store (keeps loads older than the
    // store in the vmcnt queue -> their wait never drains the store)
    float4 an, bn;
    if (it + 1 < NITER) {
      an = x4[i + 256];
      bn = g4[i + 256];
    }
    __builtin_nontemporal_store(o, &o4[i]);
    mycnt += (f0 > keyHi) + (f1 > keyHi) + (f2 > keyHi) + (f3 > keyHi);
    uint32_t li = (uint32_t)(chunk * CHUNK + i * 4);
    if (f0 >= keyLo && f0 <= keyHi) { uint32_t p = atomicAdd(&lcnt, 1u); if (p < LCAP) { lbuf[p] = ((uint64_t)f0 << 32) | li;        lval[p] = fmaxf(a.x, 0.0f); } }
    if (f1 >= keyLo && f1 <= keyHi) { uint32_t p = atomicAdd(&lcnt, 1u); if (p < LCAP) { lbuf[p] = ((uint64_t)f1 << 32) | (li + 1u); lval[p] = fmaxf(a.y, 0.0f); } }
    if (f2 >= keyLo && f2 <= keyHi) { uint32_t p = atomicAdd(&lcnt, 1u); if (p < LCAP) { lbuf[p] = ((uint64_t)f2 << 32) | (li + 2u); lval[p] = fmaxf(a.z, 0.0f); } }
    if (f3 >= keyLo && f3 <= keyHi) { uint32_t p = atomicAdd(&lcnt, 1u); if (p < LCAP) { lbuf[p] = ((uint64_t)f3 << 32) | (li + 3u); lval[p] = fmaxf(a.w, 0.0f); } }
    a = an; b = bn;
  }

  for (int off = 32; off > 0; off >>= 1) mycnt += __shfl_down(mycnt, off);
  int lane = threadIdx.x & 63, wid = threadIdx.x >> 6;
  if (lane == 0) wsum[wid] = mycnt;
  __syncthreads();
  if (threadIdx.x == 0) {
    atomicAdd(&abv[row], wsum[0] + wsum[1] + wsum[2] + wsum[3]);
    lbase = atomicAdd(&ccnt[row], lcnt < LCAP ? lcnt : (uint32_t)LCAP);
  }
  __syncthreads();
  uint32_t cnt = lcnt < LCAP ? lcnt : (uint32_t)LCAP;
  uint64_t* dst = cand + (size_t)row * (size_t)cap;
  float* dv = cval + (size_t)row * (size_t)cap;
  for (uint32_t i = threadIdx.x; i < cnt; i += 256) {
    uint32_t p = lbase + i;
    if (p < (uint32_t)cap) { dst[p] = lbuf[i]; dv[p] = lval[i]; }
  }
}

// P2: exact top-(k - above) among candidates: dynamic-shift 4096-bin radix,
// then sort boundary sub-bin by (key desc, idx asc) -- jax tie semantics.
// Reads cval (L2-resident), NOT x (except <=64 boundary ties).
__global__ __launch_bounds__(256) void k_finalize(const float* __restrict__ x,
                                                  const uint64_t* __restrict__ cand,
                                                  const float* __restrict__ cval,
                                                  const uint32_t* __restrict__ ccnt,
                                                  const uint32_t* __restrict__ abv,
                                                  const uint32_t* __restrict__ rinfo,
                                                  const int* __restrict__ kptr,
                                                  float* __restrict__ out, int cap) {
  __shared__ uint32_t h[4096];
  __shared__ uint32_t part[256];
  __shared__ uint64_t elist[ECAP];
  __shared__ uint32_t ecnt;
  __shared__ int s_cut, s_need2;
  int row = blockIdx.x;
  uint32_t m = ccnt[row];
  if (m > (uint32_t)cap) m = (uint32_t)cap;
  int need = (int)((uint32_t)(*kptr)) - (int)abv[row];
  if (need <= 0) return;
  size_t rb = (size_t)row * NCOL;
  const uint64_t* c = cand + (size_t)row * (size_t)cap;
  const float* cv = cval + (size_t)row * (size_t)cap;
  if ((uint32_t)need >= m) {  // all candidates win
    for (uint32_t i = threadIdx.x; i < m; i += 256) {
      uint32_t idx = (uint32_t)c[i];
      out[rb + idx] = cv[i];
    }
    return;
  }
  uint32_t keyLo = rinfo[row * 4 + 1];
  uint32_t range = rinfo[row * 4 + 0] - keyLo;
  int bits = 32 - __clz((int)(range | 1u));
  int shift = bits > 12 ? bits - 12 : 0;
  for (int i = threadIdx.x; i < 4096; i += 256) h[i] = 0;
  if (threadIdx.x == 0) ecnt = 0;
  __syncthreads();
  for (uint32_t i = threadIdx.x; i < m; i += 256) {
    uint32_t key = (uint32_t)(c[i] >> 32);
    atomicAdd(&h[(key - keyLo) >> shift], 1u);
  }
  __syncthreads();
  uint32_t s = 0;
  for (int j = 0; j < 16; ++j) s += h[threadIdx.x * 16 + j];
  part[threadIdx.x] = s;
  __syncthreads();
  if (threadIdx.x == 0) {
    uint32_t cum = 0;
    int seg = 255;
    for (; seg > 0; --seg) {
      if (cum + part[seg] >= (uint32_t)need) break;
      cum += part[seg];
    }
    int bin = seg * 16 + 15;
    for (; bin > seg * 16; --bin) {
      if (cum + h[bin] >= (uint32_t)need) break;
      cum += h[bin];
    }
    s_cut = bin;
    s_need2 = need - (int)cum;
  }
  __syncthreads();
  int cut = s_cut, need2 = s_need2;
  for (uint32_t i = threadIdx.x; i < m; i += 256) {
    uint64_t e = c[i];
    int bin = (int)(((uint32_t)(e >> 32) - keyLo) >> shift);
    if (bin > cut) {
      out[rb + (uint32_t)e] = cv[i];
    } else if (bin == cut) {
      uint32_t p = atomicAdd(&ecnt, 1u);
      if (p < ECAP) elist[p] = e ^ 0xFFFFFFFFull;  // key desc, idx asc under u64 desc
    }
  }
  __syncthreads();
  int mm = (int)(ecnt < (uint32_t)ECAP ? ecnt : (uint32_t)ECAP);
  for (int pass = 0; pass < mm; ++pass) {
    for (int i = threadIdx.x; 2 * i + (pass & 1) + 1 < mm; i += 256) {
      int a2 = 2 * i + (pass & 1);
      uint64_t va = elist[a2], vb = elist[a2 + 1];
      if (vb > va) { elist[a2] = vb; elist[a2 + 1] = va; }
    }
    __syncthreads();
  }
  int w = need2 < mm ? need2 : mm;
  for (int i = threadIdx.x; i < w; i += 256) {
    uint32_t idx = ~(uint32_t)elist[i];
    out[rb + idx] = fmaxf(x[rb + idx], 0.0f);
  }
}

extern "C" void kernel_launch(void* const* d_in, const int* in_sizes, int n_in,
                              void* d_out, int out_size, void* d_ws, size_t ws_size,
                              hipStream_t stream) {
  const float* x = (const float*)d_in[0];
  const float* g = (const float*)d_in[1];
  const int* kptr = (const int*)d_in[2];
  float* out = (float*)d_out;
  char* ws = (char*)d_ws;

  uint32_t* abv = (uint32_t*)(ws + ABV_OFF);
  uint32_t* ccnt = (uint32_t*)(ws + CCNT_OFF);
  uint32_t* rinfo = (uint32_t*)(ws + RINFO_OFF);
  uint32_t* hist = (uint32_t*)(ws + HIST_OFF);
  uint64_t* cand = (uint64_t*)(ws + CAND_OFF);  // overlaps hist (hist dead by then)

  // cand: 8B/entry, cval: 4B/entry -> 12B per candidate slot
  long cap_avail = ((long)ws_size - (long)CAND_OFF) / (12 * BROWS);
  int cap = cap_avail < MAXCAP ? (int)cap_avail : MAXCAP;
  if (cap < 1) cap = 1;
  float* cval = (float*)(ws + CAND_OFF + (size_t)BROWS * (size_t)cap * 8u);

  // async memset node replaces the k_zero launch (graph-capturable)
  hipMemsetAsync(ws, 0, (size_t)ZWORDS * 4u, stream);
  dim3 sgrid(SBLK, BROWS);
  k_sampleA<<<sgrid, 256, 0, stream>>>(x, g, hist);
  k_pick<<<BROWS, 1024, 0, stream>>>(hist, kptr, rinfo, abv, ccnt);
  dim3 grid(CHUNKS, BROWS);
  k_main<<<grid, 256, 0, stream>>>(x, g, rinfo, cand, cval, ccnt, abv, out, cap);
  k_finalize<<<BROWS, 256, 0, stream>>>(x, cand, cval, ccnt, abv, rinfo, kptr, out, cap);
}